// Round 1
// 112.618 us; speedup vs baseline: 1.0233x; 1.0233x over previous
//
#include <hip/hip_runtime.h>

// Pendulum2 DAE closed-form per-row solve.
// Row: coords = [x0 x1 x2 x3 | v0 v1 v2 v3]  ->  out = [v0..v3 | a0..a3]
// Derivation (M0=M1=G=10, Minv = 0.1*I):
//   a = x0-x2, b = x1-x3
//   L00 = 0.4(x0^2+x1^2); L01 = 0.4(x0*a + x1*b); L11 = 0.8(a^2+b^2)
//   R1  = -20*x1 + 2(v0^2+v1^2); R2 = 2((v0-v2)^2+(v1-v3)^2)
//   [L00 L01; L01 L11] lam = [R1; R2]  (2x2 Cramer, Kahan-compensated fp32)
//   acc = 0.1 * (F - phi_q^T lam), F = (0,-100,0,-100)
//
// R3 note: __builtin_nontemporal_* gave no win (117.1 -> 122.2 us) — reverted.
// R4 (this round): pair-shuffle coalescing. Previous version had each thread
// load float4s at byte addresses 32i and 32i+16 (stride-32 interleave): every
// VMEM instruction half-uses each 128B line, doubling TA transactions per
// useful byte. Now each thread owns ONE float4 at lane-contiguous index g
// (16B/lane, the canonical 6.3 TB/s pattern). Even g holds x of row g/2, odd
// g holds v. __shfl_xor(.,1) (quad-perm DPP, intra-wave, pairs are always
// wave-aligned since block=256) exchanges halves; both lanes compute the
// cheap closed-form solve redundantly; each lane stores the single float4
// its output slot wants (even -> v, odd -> a). Loads+stores fully coalesced.

typedef float f32x4 __attribute__((ext_vector_type(4)));

// Kahan-compensated 2x2 determinant: a*d - b*c with one extra fma.
__device__ __forceinline__ float det2x2(float a, float d, float b, float c) {
  float w = b * c;
  float e = fmaf(b, c, -w);     // exact low part of b*c
  float f = fmaf(a, d, -w);     // a*d - w, single rounding
  return f - e;                 // (a*d - b*c) to ~fp64 accuracy
}

__global__ __launch_bounds__(256) void pendulum_dae_kernel(
    const float* __restrict__ coords, float* __restrict__ out, int n4) {
  int g = blockIdx.x * blockDim.x + threadIdx.x;  // global float4 index
  if (g >= n4) return;

  const f32x4* __restrict__ in4 = (const f32x4*)coords;
  f32x4 mine = in4[g];  // lane-contiguous dwordx4: 64 lanes x 16B, stride 16

  // Exchange with partner lane (g^1). Pairs (2k,2k+1) share a wave because
  // blockDim=256 and pair boundaries align with lane pairs.
  f32x4 other;
  other.x = __shfl_xor(mine.x, 1);
  other.y = __shfl_xor(mine.y, 1);
  other.z = __shfl_xor(mine.z, 1);
  other.w = __shfl_xor(mine.w, 1);

  const bool haveX = ((g & 1) == 0);  // even float4 = x-half of row g/2
  f32x4 xv = haveX ? mine : other;    // x0 x1 x2 x3
  f32x4 vv = haveX ? other : mine;    // v0 v1 v2 v3

  float x0 = xv.x, x1 = xv.y, x2 = xv.z, x3 = xv.w;
  float v0 = vv.x, v1 = vv.y, v2 = vv.z, v3 = vv.w;

  float da = x0 - x2, db = x1 - x3;
  float dv0 = v0 - v2, dv1 = v1 - v3;

  float L00 = 0.4f * fmaf(x0, x0, x1 * x1);
  float L01 = 0.4f * fmaf(x0, da, x1 * db);
  float L11 = 0.8f * fmaf(da, da, db * db);

  float R1 = fmaf(-20.0f, x1, 2.0f * fmaf(v0, v0, v1 * v1));
  float R2 = 2.0f * fmaf(dv0, dv0, dv1 * dv1);

  // Compensated Cramer solve (handles near-singular rows without fp64).
  float det  = det2x2(L00, L11, L01, L01);
  float num1 = det2x2(L11, R1, L01, R2);
  float num2 = det2x2(L00, R2, L01, R1);
  float inv = 1.0f / det;
  float lam1 = num1 * inv;
  float lam2 = num2 * inv;

  float aR0 = -2.0f * fmaf(x0, lam1, da * lam2);
  float aR1 = fmaf(-2.0f, fmaf(x1, lam1, db * lam2), -100.0f);
  float aR2 = 2.0f * da * lam2;
  float aR3 = fmaf(2.0f * db, lam2, -100.0f);

  f32x4 av;
  av.x = 0.1f * aR0;
  av.y = 0.1f * aR1;
  av.z = 0.1f * aR2;
  av.w = 0.1f * aR3;

  // Output row k: out4[2k] = v, out4[2k+1] = a. Each lane stores its own g.
  f32x4 res = haveX ? vv : av;
  f32x4* __restrict__ out4 = (f32x4*)out;
  out4[g] = res;
}

extern "C" void kernel_launch(void* const* d_in, const int* in_sizes, int n_in,
                              void* d_out, int out_size, void* d_ws,
                              size_t ws_size, hipStream_t stream) {
  // d_in[0] = t (unused, size 1), d_in[1] = coords (bs*8 fp32)
  const float* coords = (const float*)d_in[1];
  float* out = (float*)d_out;
  int n4 = in_sizes[1] / 4;  // total float4s (2 per row)
  int block = 256;
  int grid = (n4 + block - 1) / block;
  pendulum_dae_kernel<<<grid, block, 0, stream>>>(coords, out, n4);
}